// Round 11
// baseline (920.520 us; speedup 1.0000x reference)
//
#include <hip/hip_runtime.h>
#include <hip/hip_bf16.h>
#include <math.h>

#define HW 64
#define NPIX 4096
#define NB 16
#define NCH 1792
#define PW 72                 // padded width (units of 8ch)
#define PROWS 70              // padded rows (64 + 2*3 halo)
#define PLANE (PROWS * PW)    // 5040 units per 8-ch plane

typedef __bf16 bf16;
typedef __bf16 bf16x8 __attribute__((ext_vector_type(8)));
typedef float f32x4 __attribute__((ext_vector_type(4)));

struct PtrQuad { const float* p[4]; };

constexpr size_t PLE = (size_t)PLANE * 8;      // bf16 elements per plane

// x-part MFMA steps: 4 taps x 8ch per K=32 step
constexpr int nstepx(int K) { return (K * K + 3) / 4; }

// repacked-weight sizes (bf16 elements) per branch:
//   act part [K*K][ACT_CHUNKS][COUT][32] + x part [NSX][COUT][32]
constexpr size_t W3SZ = (size_t)nstepx(3) * 64 * 32;                        // 6144
constexpr size_t W5SZ = (size_t)25 * 2 * 128 * 32 + nstepx(5) * 128 * 32;   // 233472
constexpr size_t W7SZ = (size_t)49 * 4 * 256 * 32 + nstepx(7) * 256 * 32;   // 1712128
constexpr size_t WBR  = W3SZ + W5SZ + W7SZ;                                 // 1951744

// ---------------------------------------------------------------------------
__global__ __launch_bounds__(256) void init_kernel(float* __restrict__ gap_sum,
                                                   float* __restrict__ dct_sum,
                                                   float* __restrict__ dctw) {
    int tid = blockIdx.x * 256 + threadIdx.x;
    if (tid < NB * NCH) { gap_sum[tid] = 0.f; dct_sum[tid] = 0.f; }
    if (blockIdx.x == 0 && threadIdx.x < HW) {
        int i = threadIdx.x;
        float s = 0.f;
        for (int u = 0; u < 5; ++u) {
            float scale = (u == 0) ? 0.125f : 0.17677669529663687f;
            s += cosf(3.14159265358979323846f * (2.f * i + 1.f) * u / 128.f) * scale;
        }
        dctw[i] = s * 0.2f;
    }
}

// halo-only zeroing of planar-8 scratch (interiors are fully rewritten each
// call: prep_x writes full 16B units; conv epilogues write all 8 ch/pixel).
// Halo units/plane: rows{0-2,67-69} full (432) + rows 3-66 x cols{0-2,67-71} (512) = 944.
__global__ __launch_bounds__(256) void halo_zero(bf16* __restrict__ base, int nplanes) {
    int tid = blockIdx.x * 256 + threadIdx.x;
    if (tid >= nplanes * 944) return;
    int p = tid / 944, u = tid - p * 944;
    int row, col;
    if (u < 432) { row = u / PW; col = u - row * PW; if (row >= 3) row += 64; }
    else { int v = u - 432; row = 3 + (v >> 3); int c = v & 7; col = (c < 3) ? c : 64 + c; }
    bf16x8 z;
#pragma unroll
    for (int j = 0; j < 8; ++j) z[j] = (bf16)0.f;
    *(bf16x8*)(base + ((size_t)p * PLANE + row * PW + col) * 8) = z;
}

// x (fp32 NCHW) -> padded planar-8: xp[b][g][PLANE][8], ch0-2 real, ch3-7 = 0
__global__ __launch_bounds__(256) void prep_x_kernel(const float* __restrict__ x,
                                                     bf16* __restrict__ xp) {
    int tid = blockIdx.x * 256 + threadIdx.x;      // NB*2*NPIX
    if (tid >= NB * 2 * NPIX) return;
    int pix = tid & (NPIX - 1);
    int g = (tid >> 12) & 1;
    int b = tid >> 13;
    int h = pix >> 6, w = pix & 63;
    bf16x8 v;
#pragma unroll
    for (int j = 0; j < 8; ++j) v[j] = (bf16)0.f;
    for (int c = 0; c < 3; ++c)
        v[c] = (bf16)x[((size_t)(b * 6 + g * 3 + c)) * NPIX + pix];
    *(bf16x8*)(xp + ((size_t)(b * 2 + g) * PLANE + (size_t)(h + 3) * PW + (w + 3)) * 8) = v;
}

// weight repack, 4 branches: act part [K*K][ACT_CHUNKS][COUT][32] (ci=chunk*32+cc)
// + x part [NSX][COUT][32] where 32 = slot(4 taps)*8 + ch (ch<3 real, else 0)
template <int K, int ACT_CHUNKS, int CIN_ACT, int COUT>
__global__ __launch_bounds__(256) void prep_w_all(PtrQuad src, bf16* __restrict__ dst) {
    constexpr int CIN = CIN_ACT + 3;
    constexpr int KK = K * K;
    constexpr int NSX = (KK + 3) / 4;
    constexpr int ACT_TOT = KK * ACT_CHUNKS * COUT * 32;
    constexpr int X_TOT = NSX * COUT * 32;
    constexpr int TOT = ACT_TOT + X_TOT;
    constexpr int ACD = ACT_CHUNKS ? ACT_CHUNKS : 1;
    int tid = blockIdx.x * 256 + threadIdx.x;
    if (tid >= 4 * TOT) return;
    int br = tid / TOT;
    int idx = tid - br * TOT;
    const float* w = src.p[br];
    float v;
    if (idx < ACT_TOT) {
        int cc = idx & 31;
        int co = (idx >> 5) % COUT;
        int rest = idx / (32 * COUT);
        int chunk = rest % ACD;
        int ks = rest / ACD;
        int ky = ks / K, kx = ks % K;
        v = w[(((size_t)co * CIN + chunk * 32 + cc) * K + ky) * K + kx];
    } else {
        int xi = idx - ACT_TOT;
        int j = xi & 7;
        int slot = (xi >> 3) & 3;
        int co = (xi >> 5) % COUT;
        int s = xi / (32 * COUT);
        int tap = 4 * s + slot;
        if (tap < KK && j < 3) {
            int ky = tap / K, kx = tap % K;
            v = w[(((size_t)co * CIN + CIN_ACT + j) * K + ky) * K + kx];
        } else v = 0.f;
    }
    dst[(size_t)br * WBR + idx] = (bf16)v;
}

// ---------------------------------------------------------------------------
// Implicit-GEMM conv, MFMA 16x16x32 bf16. R11 = R10 with a smaller n-tile:
// wave tile 8m x 2n (NBLK=64, acc = 64 VGPRs) so total regs/wave ~164 ->
// 3 waves/SIMD (launch_bounds min-waves=3). Rationale: MfmaUtil pinned at
// ~64% across R3/R7/R10 at 2 waves/SIMD = latency-bound; third wave adds
// TLP. B-bytes/MFMA stays 128 (R5's failure was 256); LDS A-traffic
// 512 B/MFMA -> 105 B/cyc/CU at MFMA peak, under the 128 B/cyc LDS ceiling.
// Everything else identical to R10 (planar DMA staging, tap-packed x-chunk,
// XCD branch pinning, JIT loads).
// ---------------------------------------------------------------------------
template <int K, int ACT_CHUNKS, int COUT, int NBLK, bool STORE>
__global__ __launch_bounds__(256, 3) void conv_mfma(
    const bf16* __restrict__ act_in,   // [lbr*NB+b][ACT_CHUNKS*4 planes][PLANE][8]
    const bf16* __restrict__ xpad,     // [b][g][PLANE][8]
    const bf16* __restrict__ wall, size_t stage_woff,
    PtrQuad biasq,
    bf16* __restrict__ act_out,        // [lbr*NB+b][COUT/8 planes][PLANE][8]
    float* __restrict__ gap_sum, float* __restrict__ dct_sum,
    int stage_coff, const float* __restrict__ dctw, int br0,
    int br_mask, int br_bits)
{
    constexpr int PAD = K / 2;
    constexpr int COFF = 3 - PAD;          // layout pad (3) minus conv pad
    constexpr int HR = 4 + K - 1;          // staged rows (4 out rows + halo)
    constexpr int UN = HR * PW;            // 16B units in one staged plane-tile
    constexpr int NI = (UN + 63) / 64;     // DMA insts per wave (act: 1 seg/wave)
    constexpr int WN = NBLK / 32;          // n-frags per wave
    constexpr int KK = K * K;
    constexpr int NSX = (KK + 3) / 4;      // x-part MFMA steps
    constexpr int CW = ACT_CHUNKS * COUT * 32;   // act tap stride in wrep
    constexpr int XOFF = KK * ACT_CHUNKS * COUT * 32;
    constexpr int OPL = COUT / 8;          // output planes

    __shared__ __align__(16) bf16 s_in[4 * HR * PW * 8];

    const int tid = threadIdx.x;
    const int lane = tid & 63;
    const int wv = tid >> 6;
    const int wavem = wv >> 1;             // 0..1 -> rows [wavem*2, wavem*2+2)
    const int wn = wv & 1;
    const int q = lane >> 4;
    const int ln = lane & 15;

    const int bx = blockIdx.x;
    const int lbr = bx & br_mask;          // branch in LOW bits -> XCD pinning
    const int row = bx >> br_bits;
    const int b = blockIdx.z;
    const int br = br0 + lbr;
    const int g = br >> 1;

    const int o0 = row * 4;
    const int prow0 = o0 + COFF;           // first staged padded row
    const int n0 = blockIdx.y * NBLK + wn * (NBLK / 2);

    const bf16* wrep = wall + (size_t)br * WBR + stage_woff;
    const float* bias = biasq.p[br];
    const size_t img = (size_t)(lbr * NB + b);

    // A-frag base offsets for act chunks (q = k-segment plane)
    int abase[8];
#pragma unroll
    for (int t = 0; t < 8; ++t) {
        int lr = wavem * 2 + (t >> 2);
        int ct = (t & 3) * 16;
        abase[t] = ((q * HR + lr) * PW + ct + ln + COFF) * 8;
    }

    f32x4 acc[8][WN];
#pragma unroll
    for (int t = 0; t < 8; ++t)
#pragma unroll
        for (int u = 0; u < WN; ++u) acc[t][u] = f32x4{0.f, 0.f, 0.f, 0.f};

    // ---- act 32-ch chunks ----
#pragma unroll 1
    for (int chunk = 0; chunk < ACT_CHUNKS; ++chunk) {
        __syncthreads();                   // buffer free (prev reads done)
        {
            const bf16* pl = act_in + (img * (ACT_CHUNKS * 4) + chunk * 4 + wv) * PLE;
            const bf16* gb = pl + (size_t)prow0 * PW * 8;
            bf16* lb = s_in + (size_t)wv * HR * PW * 8;
#pragma unroll
            for (int i = 0; i < NI; ++i) {
                int u = i * 64 + lane;
                if (UN % 64 == 0 || u < UN)
                    __builtin_amdgcn_global_load_lds(
                        (const __attribute__((address_space(1))) void*)(gb + (size_t)u * 8),
                        (__attribute__((address_space(3))) void*)(lb + i * 512),
                        16, 0, 0);
            }
        }
        __syncthreads();                   // DMA landed

        const bf16* wchunk = wrep + ((size_t)chunk * COUT + n0) * 32 + ln * 32 + q * 8;

#pragma unroll 1
        for (int ky = 0; ky < K; ++ky) {
            const int kyoff = ky * PW * 8;
#pragma unroll
            for (int kx = 0; kx < K; ++kx) {
                const bf16* wstep = wchunk + (size_t)(ky * K + kx) * CW;
                bf16x8 bfr[WN];
#pragma unroll
                for (int u = 0; u < WN; ++u)
                    bfr[u] = *(const bf16x8*)(wstep + u * 512);
                const int koff = kyoff + kx * 8;
                bf16x8 afr[8];
#pragma unroll
                for (int t = 0; t < 8; ++t)
                    afr[t] = *(const bf16x8*)(s_in + abase[t] + koff);
#pragma unroll
                for (int t = 0; t < 8; ++t)
#pragma unroll
                    for (int u = 0; u < WN; ++u)
                        acc[t][u] = __builtin_amdgcn_mfma_f32_16x16x32_bf16(
                            afr[t], bfr[u], acc[t][u], 0, 0, 0);
            }
        }
    }

    // ---- x tap-packed part: NSX steps of (4 taps x 8 ch) ----
    __syncthreads();
    {
        const bf16* gb = xpad + (size_t)(b * 2 + g) * PLE + (size_t)prow0 * PW * 8;
        constexpr int PERW = (UN + 3) / 4;             // units per wave
        const int u0 = wv * PERW;
        bf16* lb = s_in + (size_t)u0 * 8;
        constexpr int NIX = (PERW + 63) / 64;
#pragma unroll
        for (int i = 0; i < NIX; ++i) {
            int u = i * 64 + lane;
            if (u < PERW && u0 + u < UN)
                __builtin_amdgcn_global_load_lds(
                    (const __attribute__((address_space(1))) void*)(gb + (size_t)(u0 + u) * 8),
                    (__attribute__((address_space(3))) void*)(lb + i * 512),
                    16, 0, 0);
        }
    }
    __syncthreads();

    {
        int xabase[8];
#pragma unroll
        for (int t = 0; t < 8; ++t) {
            int lr = wavem * 2 + (t >> 2);
            int ct = (t & 3) * 16;
            xabase[t] = (lr * PW + ct + ln + COFF) * 8;
        }
        const bf16* wx = wrep + XOFF + (size_t)n0 * 32 + ln * 32 + q * 8;
#pragma unroll
        for (int s = 0; s < NSX; ++s) {
            int tap = 4 * s + q;                       // lane-quad = tap-slot
            if (tap > KK - 1) tap = KK - 1;            // pad slots: B = 0
            int ky = tap / K;
            int kx = tap - ky * K;
            int xoff = (ky * PW + kx) * 8;
            const bf16* ws = wx + (size_t)s * COUT * 32;
            bf16x8 bfr[WN];
#pragma unroll
            for (int u = 0; u < WN; ++u)
                bfr[u] = *(const bf16x8*)(ws + u * 512);
            bf16x8 afr[8];
#pragma unroll
            for (int t = 0; t < 8; ++t)
                afr[t] = *(const bf16x8*)(s_in + xabase[t] + xoff);
#pragma unroll
            for (int t = 0; t < 8; ++t)
#pragma unroll
                for (int u = 0; u < WN; ++u)
                    acc[t][u] = __builtin_amdgcn_mfma_f32_16x16x32_bf16(
                        afr[t], bfr[u], acc[t][u], 0, 0, 0);
        }
    }

    // ---- epilogue: bias + relu (+store) + gap/dct reduction ----
    float gsum[WN], dsum[WN], bv[WN];
#pragma unroll
    for (int u = 0; u < WN; ++u) {
        gsum[u] = 0.f; dsum[u] = 0.f;
        bv[u] = bias[n0 + u * 16 + ln];
    }

#pragma unroll
    for (int t = 0; t < 8; ++t) {
        const int lr = wavem * 2 + (t >> 2);
        const int gr = o0 + lr;
        const float wrow = dctw[gr];
        const int ct = (t & 3) * 16;
#pragma unroll
        for (int r = 0; r < 4; ++r) {
            const int gc = ct + q * 4 + r;         // C/D: m = (lane>>4)*4 + reg
            const float wcd = dctw[gc] * wrow;
#pragma unroll
            for (int u = 0; u < WN; ++u) {
                float v = fmaxf(acc[t][u][r] + bv[u], 0.f);
                if constexpr (STORE) {
                    int ch = n0 + u * 16 + ln;
                    act_out[(img * OPL + (ch >> 3)) * PLE +
                            ((size_t)(gr + 3) * PW + (gc + 3)) * 8 + (ch & 7)] = (bf16)v;
                }
                gsum[u] += v;
                dsum[u] = fmaf(v, wcd, dsum[u]);
            }
        }
    }

    const int cb = br * 448 + stage_coff;
#pragma unroll
    for (int u = 0; u < WN; ++u) {
        float gv = gsum[u], dv = dsum[u];
        gv += __shfl_xor(gv, 16, 64); gv += __shfl_xor(gv, 32, 64);
        dv += __shfl_xor(dv, 16, 64); dv += __shfl_xor(dv, 32, 64);
        if (q == 0) {
            int ch = cb + n0 + u * 16 + ln;
            atomicAdd(&gap_sum[b * NCH + ch], gv);
            atomicAdd(&dct_sum[b * NCH + ch], dv);
        }
    }
}

// ---------------------------------------------------------------------------
__global__ __launch_bounds__(256) void head_kernel(
    const float* __restrict__ gap_sum, const float* __restrict__ dct_sum,
    const float* __restrict__ gap_w, const float* __restrict__ gap_b,
    const float* __restrict__ dct_w, const float* __restrict__ dct_b,
    const float* __restrict__ gamma, const float* __restrict__ beta,
    const float* __restrict__ mean, const float* __restrict__ var,
    float* __restrict__ out)
{
    const int blk = blockIdx.x;
    const int b = blk / 24;
    const int rem = blk - b * 24;
    const int kind = rem / 12;
    const int i = rem - kind * 12;
    const int tid = threadIdx.x;

    float partial = 0.f;
    if (kind == 0) {
        for (int cc = tid; cc < NCH; cc += 256)
            partial += gap_sum[b * NCH + cc] * (1.f / 4096.f) * gap_w[i * NCH + cc];
    } else {
        for (int cc = tid; cc < NCH; cc += 256) {
            float f = dct_sum[b * NCH + cc];
            f = gamma[cc] * (f - mean[cc]) * rsqrtf(var[cc] + 1e-5f) + beta[cc];
            partial += f * dct_w[i * NCH + cc];
        }
    }
#pragma unroll
    for (int off = 32; off > 0; off >>= 1) partial += __shfl_down(partial, off, 64);
    __shared__ float red[4];
    if ((tid & 63) == 0) red[tid >> 6] = partial;
    __syncthreads();
    if (tid == 0) {
        float tot = red[0] + red[1] + red[2] + red[3];
        tot += (kind == 0 ? gap_b[i] : dct_b[i]);
        out[kind * (NB * 12) + b * 12 + i] = tot;
    }
}

// ---------------------------------------------------------------------------
extern "C" void kernel_launch(void* const* d_in, const int* in_sizes, int n_in,
                              void* d_out, int out_size, void* d_ws, size_t ws_size,
                              hipStream_t stream)
{
    const float* x = (const float*)d_in[0];

    float* fws = (float*)d_ws;
    float* dctw    = fws;                      // 64
    float* gap_sum = fws + 64;                 // 16*1792
    float* dct_sum = gap_sum + NB * NCH;       // 16*1792
    bf16* bws = (bf16*)(dct_sum + NB * NCH);   // 229,632 B offset (16B aligned)

    const size_t WALL_E = 4 * WBR;                 // 7,806,976
    const size_t XP_E   = (size_t)NB * 2 * PLE;    // 1,290,240 (single plane/g)
    const size_t A3_BR  = (size_t)NB * 8 * PLE;    // per branch
    const size_t A5_BR  = (size_t)NB * 16 * PLE;   // per branch

    const size_t fixed_b = 229632 + 2 * (WALL_E + XP_E);
    int nbr = 1, br_bits = 0;
    if (ws_size >= fixed_b + 2 * 4 * (A3_BR + A5_BR)) { nbr = 4; br_bits = 2; }
    else if (ws_size >= fixed_b + 2 * 2 * (A3_BR + A5_BR)) { nbr = 2; br_bits = 1; }
    const int br_mask = nbr - 1;

    bf16* wall = bws;
    bf16* xp   = wall + WALL_E;
    bf16* a3p  = xp + XP_E;
    bf16* a5p  = a3p + (size_t)nbr * A3_BR;

    hipLaunchKernelGGL(init_kernel, dim3((NB * NCH + 255) / 256), dim3(256), 0, stream,
                       gap_sum, dct_sum, dctw);

    // halo-only zeroing of xp + a3 + a5 (contiguous planar-8 planes)
    const int nplanes = NB * 2 + nbr * NB * (8 + 16);
    hipLaunchKernelGGL(halo_zero, dim3((nplanes * 944 + 255) / 256), dim3(256), 0, stream,
                       xp, nplanes);

    hipLaunchKernelGGL(prep_x_kernel, dim3((NB * 2 * NPIX) / 256), dim3(256), 0, stream, x, xp);

    PtrQuad w3q = {{(const float*)d_in[1], (const float*)d_in[7], (const float*)d_in[13], (const float*)d_in[19]}};
    PtrQuad b3q = {{(const float*)d_in[2], (const float*)d_in[8], (const float*)d_in[14], (const float*)d_in[20]}};
    PtrQuad w5q = {{(const float*)d_in[3], (const float*)d_in[9], (const float*)d_in[15], (const float*)d_in[21]}};
    PtrQuad b5q = {{(const float*)d_in[4], (const float*)d_in[10], (const float*)d_in[16], (const float*)d_in[22]}};
    PtrQuad w7q = {{(const float*)d_in[5], (const float*)d_in[11], (const float*)d_in[17], (const float*)d_in[23]}};
    PtrQuad b7q = {{(const float*)d_in[6], (const float*)d_in[12], (const float*)d_in[18], (const float*)d_in[24]}};

    hipLaunchKernelGGL((prep_w_all<3, 0, 0, 64>), dim3((4 * W3SZ + 255) / 256), dim3(256), 0, stream,
                       w3q, wall);
    hipLaunchKernelGGL((prep_w_all<5, 2, 64, 128>), dim3((4 * W5SZ + 255) / 256), dim3(256), 0, stream,
                       w5q, wall + W3SZ);
    hipLaunchKernelGGL((prep_w_all<7, 4, 128, 256>), dim3((4 * W7SZ + 255) / 256), dim3(256), 0, stream,
                       w7q, wall + W3SZ + W5SZ);

    for (int br0 = 0; br0 < 4; br0 += nbr) {
        hipLaunchKernelGGL((conv_mfma<3, 0, 64, 64, true>), dim3(16 * nbr, 1, NB), dim3(256), 0, stream,
                           (const bf16*)nullptr, xp, wall, 0, b3q,
                           a3p, gap_sum, dct_sum, 0, dctw, br0, br_mask, br_bits);
        hipLaunchKernelGGL((conv_mfma<5, 2, 128, 64, true>), dim3(16 * nbr, 2, NB), dim3(256), 0, stream,
                           a3p, xp, wall, W3SZ, b5q,
                           a5p, gap_sum, dct_sum, 64, dctw, br0, br_mask, br_bits);
        hipLaunchKernelGGL((conv_mfma<7, 4, 256, 64, false>), dim3(16 * nbr, 4, NB), dim3(256), 0, stream,
                           a5p, xp, wall, W3SZ + W5SZ, b7q,
                           (bf16*)nullptr, gap_sum, dct_sum, 192, dctw, br0, br_mask, br_bits);
    }

    hipLaunchKernelGGL(head_kernel, dim3(NB * 24), dim3(256), 0, stream,
                       gap_sum, dct_sum,
                       (const float*)d_in[25], (const float*)d_in[26],
                       (const float*)d_in[27], (const float*)d_in[28],
                       (const float*)d_in[29], (const float*)d_in[30],
                       (const float*)d_in[31], (const float*)d_in[32],
                       (float*)d_out);
}

// Round 12
// 879.166 us; speedup vs baseline: 1.0470x; 1.0470x over previous
//
#include <hip/hip_runtime.h>
#include <hip/hip_bf16.h>
#include <math.h>

#define HW 64
#define NPIX 4096
#define NB 16
#define NCH 1792
#define PW 72                 // padded width (units of 8ch)
#define PROWS 70              // padded rows (64 + 2*3 halo)
#define PLANE (PROWS * PW)    // 5040 units per 8-ch plane

typedef __bf16 bf16;
typedef __bf16 bf16x8 __attribute__((ext_vector_type(8)));
typedef float f32x4 __attribute__((ext_vector_type(4)));

struct PtrQuad { const float* p[4]; };

constexpr size_t PLE = (size_t)PLANE * 8;      // bf16 elements per plane

// x-part MFMA steps: 4 taps x 8ch per K=32 step
constexpr int nstepx(int K) { return (K * K + 3) / 4; }

// repacked-weight sizes (bf16 elements) per branch:
//   act part [K*K][ACT_CHUNKS][COUT][32] + x part [NSX][COUT][32]
constexpr size_t W3SZ = (size_t)nstepx(3) * 64 * 32;                        // 6144
constexpr size_t W5SZ = (size_t)25 * 2 * 128 * 32 + nstepx(5) * 128 * 32;   // 233472
constexpr size_t W7SZ = (size_t)49 * 4 * 256 * 32 + nstepx(7) * 256 * 32;   // 1712128
constexpr size_t WBR  = W3SZ + W5SZ + W7SZ;                                 // 1951744

// ---------------------------------------------------------------------------
__global__ __launch_bounds__(256) void init_kernel(float* __restrict__ gap_sum,
                                                   float* __restrict__ dct_sum,
                                                   float* __restrict__ dctw) {
    int tid = blockIdx.x * 256 + threadIdx.x;
    if (tid < NB * NCH) { gap_sum[tid] = 0.f; dct_sum[tid] = 0.f; }
    if (blockIdx.x == 0 && threadIdx.x < HW) {
        int i = threadIdx.x;
        float s = 0.f;
        for (int u = 0; u < 5; ++u) {
            float scale = (u == 0) ? 0.125f : 0.17677669529663687f;
            s += cosf(3.14159265358979323846f * (2.f * i + 1.f) * u / 128.f) * scale;
        }
        dctw[i] = s * 0.2f;
    }
}

// halo-only zeroing of planar-8 scratch (interiors are fully rewritten each
// call: prep_x writes full 16B units; conv epilogues write all 8 ch/pixel).
// Halo units/plane: rows{0-2,67-69} full (432) + rows 3-66 x cols{0-2,67-71} (512) = 944.
__global__ __launch_bounds__(256) void halo_zero(bf16* __restrict__ base, int nplanes) {
    int tid = blockIdx.x * 256 + threadIdx.x;
    if (tid >= nplanes * 944) return;
    int p = tid / 944, u = tid - p * 944;
    int row, col;
    if (u < 432) { row = u / PW; col = u - row * PW; if (row >= 3) row += 64; }
    else { int v = u - 432; row = 3 + (v >> 3); int c = v & 7; col = (c < 3) ? c : 64 + c; }
    bf16x8 z;
#pragma unroll
    for (int j = 0; j < 8; ++j) z[j] = (bf16)0.f;
    *(bf16x8*)(base + ((size_t)p * PLANE + row * PW + col) * 8) = z;
}

// x (fp32 NCHW) -> padded planar-8: xp[b][g][PLANE][8], ch0-2 real, ch3-7 = 0
__global__ __launch_bounds__(256) void prep_x_kernel(const float* __restrict__ x,
                                                     bf16* __restrict__ xp) {
    int tid = blockIdx.x * 256 + threadIdx.x;      // NB*2*NPIX
    if (tid >= NB * 2 * NPIX) return;
    int pix = tid & (NPIX - 1);
    int g = (tid >> 12) & 1;
    int b = tid >> 13;
    int h = pix >> 6, w = pix & 63;
    bf16x8 v;
#pragma unroll
    for (int j = 0; j < 8; ++j) v[j] = (bf16)0.f;
    for (int c = 0; c < 3; ++c)
        v[c] = (bf16)x[((size_t)(b * 6 + g * 3 + c)) * NPIX + pix];
    *(bf16x8*)(xp + ((size_t)(b * 2 + g) * PLANE + (size_t)(h + 3) * PW + (w + 3)) * 8) = v;
}

// weight repack, 4 branches: act part [K*K][ACT_CHUNKS][COUT][32] (ci=chunk*32+cc)
// + x part [NSX][COUT][32] where 32 = slot(4 taps)*8 + ch (ch<3 real, else 0)
template <int K, int ACT_CHUNKS, int CIN_ACT, int COUT>
__global__ __launch_bounds__(256) void prep_w_all(PtrQuad src, bf16* __restrict__ dst) {
    constexpr int CIN = CIN_ACT + 3;
    constexpr int KK = K * K;
    constexpr int NSX = (KK + 3) / 4;
    constexpr int ACT_TOT = KK * ACT_CHUNKS * COUT * 32;
    constexpr int X_TOT = NSX * COUT * 32;
    constexpr int TOT = ACT_TOT + X_TOT;
    constexpr int ACD = ACT_CHUNKS ? ACT_CHUNKS : 1;
    int tid = blockIdx.x * 256 + threadIdx.x;
    if (tid >= 4 * TOT) return;
    int br = tid / TOT;
    int idx = tid - br * TOT;
    const float* w = src.p[br];
    float v;
    if (idx < ACT_TOT) {
        int cc = idx & 31;
        int co = (idx >> 5) % COUT;
        int rest = idx / (32 * COUT);
        int chunk = rest % ACD;
        int ks = rest / ACD;
        int ky = ks / K, kx = ks % K;
        v = w[(((size_t)co * CIN + chunk * 32 + cc) * K + ky) * K + kx];
    } else {
        int xi = idx - ACT_TOT;
        int j = xi & 7;
        int slot = (xi >> 3) & 3;
        int co = (xi >> 5) % COUT;
        int s = xi / (32 * COUT);
        int tap = 4 * s + slot;
        if (tap < KK && j < 3) {
            int ky = tap / K, kx = tap % K;
            v = w[(((size_t)co * CIN + CIN_ACT + j) * K + ky) * K + kx];
        } else v = 0.f;
    }
    dst[(size_t)br * WBR + idx] = (bf16)v;
}

// ---------------------------------------------------------------------------
// Implicit-GEMM conv, MFMA 16x16x32 bf16. R12 = R10 config (the best: 881us;
// NBLK=128, 2 blocks/CU — R11's 3-wave variant proved TLP isn't the limit)
// with the x-part staging folded into the LAST act chunk's barrier pair:
// x plane DMAs into LDS segment 4 alongside act segs 0-3, so x-compute needs
// no extra barriers and its DMA latency hides behind 49 taps of MFMA.
// Keeps: planar global_load_lds staging, tap-packed x-chunk (4 taps x 8ch
// per K=32 step), XCD branch pinning, JIT A/B loads (B-prefetch failed 3x).
// ---------------------------------------------------------------------------
template <int K, int ACT_CHUNKS, int COUT, int NBLK, bool STORE>
__global__ __launch_bounds__(256, 2) void conv_mfma(
    const bf16* __restrict__ act_in,   // [lbr*NB+b][ACT_CHUNKS*4 planes][PLANE][8]
    const bf16* __restrict__ xpad,     // [b][g][PLANE][8]
    const bf16* __restrict__ wall, size_t stage_woff,
    PtrQuad biasq,
    bf16* __restrict__ act_out,        // [lbr*NB+b][COUT/8 planes][PLANE][8]
    float* __restrict__ gap_sum, float* __restrict__ dct_sum,
    int stage_coff, const float* __restrict__ dctw, int br0,
    int br_mask, int br_bits)
{
    constexpr int PAD = K / 2;
    constexpr int COFF = 3 - PAD;          // layout pad (3) minus conv pad
    constexpr int HR = 4 + K - 1;          // staged rows (4 out rows + halo)
    constexpr int UN = HR * PW;            // 16B units in one staged plane-tile
    constexpr int NI = (UN + 63) / 64;     // DMA insts per wave (act: 1 seg/wave)
    constexpr int WN = NBLK / 32;          // n-frags per wave
    constexpr int KK = K * K;
    constexpr int NSX = (KK + 3) / 4;      // x-part MFMA steps
    constexpr int CW = ACT_CHUNKS * COUT * 32;   // act tap stride in wrep
    constexpr int XOFF = KK * ACT_CHUNKS * COUT * 32;
    constexpr int OPL = COUT / 8;          // output planes
    constexpr int XSEG = ACT_CHUNKS ? 4 : 0;     // x plane's LDS segment
    constexpr int NSEG = ACT_CHUNKS ? 5 : 1;

    __shared__ __align__(16) bf16 s_in[NSEG * HR * PW * 8];

    const int tid = threadIdx.x;
    const int lane = tid & 63;
    const int wv = tid >> 6;
    const int wavem = wv >> 1;             // 0..1 -> rows [wavem*2, wavem*2+2)
    const int wn = wv & 1;
    const int q = lane >> 4;
    const int ln = lane & 15;

    const int bx = blockIdx.x;
    const int lbr = bx & br_mask;          // branch in LOW bits -> XCD pinning
    const int row = bx >> br_bits;
    const int b = blockIdx.z;
    const int br = br0 + lbr;
    const int g = br >> 1;

    const int o0 = row * 4;
    const int prow0 = o0 + COFF;           // first staged padded row
    const int n0 = blockIdx.y * NBLK + wn * (NBLK / 2);

    const bf16* wrep = wall + (size_t)br * WBR + stage_woff;
    const float* bias = biasq.p[br];
    const size_t img = (size_t)(lbr * NB + b);

    // A-frag base offsets for act chunks (q = k-segment plane)
    int abase[8];
#pragma unroll
    for (int t = 0; t < 8; ++t) {
        int lr = wavem * 2 + (t >> 2);
        int ct = (t & 3) * 16;
        abase[t] = ((q * HR + lr) * PW + ct + ln + COFF) * 8;
    }

    f32x4 acc[8][WN];
#pragma unroll
    for (int t = 0; t < 8; ++t)
#pragma unroll
        for (int u = 0; u < WN; ++u) acc[t][u] = f32x4{0.f, 0.f, 0.f, 0.f};

    const bf16* xgb = xpad + (size_t)(b * 2 + g) * PLE + (size_t)prow0 * PW * 8;
    constexpr int PERW = (UN + 3) / 4;     // x units per wave
    constexpr int NIX = (PERW + 63) / 64;

    // ---- act 32-ch chunks (x plane rides the last chunk's barrier) ----
#pragma unroll 1
    for (int chunk = 0; chunk < ACT_CHUNKS; ++chunk) {
        __syncthreads();                   // buffer free (prev reads done)
        {
            const bf16* pl = act_in + (img * (ACT_CHUNKS * 4) + chunk * 4 + wv) * PLE;
            const bf16* gb = pl + (size_t)prow0 * PW * 8;
            bf16* lb = s_in + (size_t)wv * HR * PW * 8;
#pragma unroll
            for (int i = 0; i < NI; ++i) {
                int u = i * 64 + lane;
                if (UN % 64 == 0 || u < UN)
                    __builtin_amdgcn_global_load_lds(
                        (const __attribute__((address_space(1))) void*)(gb + (size_t)u * 8),
                        (__attribute__((address_space(3))) void*)(lb + i * 512),
                        16, 0, 0);
            }
        }
        if (chunk == ACT_CHUNKS - 1) {     // stage x plane into segment 4
            const int u0 = wv * PERW;
            bf16* lb = s_in + (size_t)(XSEG * HR * PW + u0) * 8;
#pragma unroll
            for (int i = 0; i < NIX; ++i) {
                int u = i * 64 + lane;
                if (u < PERW && u0 + u < UN)
                    __builtin_amdgcn_global_load_lds(
                        (const __attribute__((address_space(1))) void*)(xgb + (size_t)(u0 + u) * 8),
                        (__attribute__((address_space(3))) void*)(lb + i * 512),
                        16, 0, 0);
            }
        }
        __syncthreads();                   // DMA landed

        const bf16* wchunk = wrep + ((size_t)chunk * COUT + n0) * 32 + ln * 32 + q * 8;

#pragma unroll 1
        for (int ky = 0; ky < K; ++ky) {
            const int kyoff = ky * PW * 8;
#pragma unroll
            for (int kx = 0; kx < K; ++kx) {
                const bf16* wstep = wchunk + (size_t)(ky * K + kx) * CW;
                bf16x8 bfr[WN];
#pragma unroll
                for (int u = 0; u < WN; ++u)
                    bfr[u] = *(const bf16x8*)(wstep + u * 512);
                const int koff = kyoff + kx * 8;
                bf16x8 afr[8];
#pragma unroll
                for (int t = 0; t < 8; ++t)
                    afr[t] = *(const bf16x8*)(s_in + abase[t] + koff);
#pragma unroll
                for (int t = 0; t < 8; ++t)
#pragma unroll
                    for (int u = 0; u < WN; ++u)
                        acc[t][u] = __builtin_amdgcn_mfma_f32_16x16x32_bf16(
                            afr[t], bfr[u], acc[t][u], 0, 0, 0);
            }
        }
    }

    // ---- x tap-packed part: NSX steps of (4 taps x 8 ch) ----
    if constexpr (ACT_CHUNKS == 0) {       // conv3: stage x alone
        __syncthreads();
        {
            const int u0 = wv * PERW;
            bf16* lb = s_in + (size_t)u0 * 8;
#pragma unroll
            for (int i = 0; i < NIX; ++i) {
                int u = i * 64 + lane;
                if (u < PERW && u0 + u < UN)
                    __builtin_amdgcn_global_load_lds(
                        (const __attribute__((address_space(1))) void*)(xgb + (size_t)(u0 + u) * 8),
                        (__attribute__((address_space(3))) void*)(lb + i * 512),
                        16, 0, 0);
            }
        }
        __syncthreads();
    }
    // (ACT_CHUNKS>0: x already landed before the last chunk's barrier)

    {
        int xabase[8];
#pragma unroll
        for (int t = 0; t < 8; ++t) {
            int lr = wavem * 2 + (t >> 2);
            int ct = (t & 3) * 16;
            xabase[t] = ((XSEG * HR + lr) * PW + ct + ln + COFF) * 8;
        }
        const bf16* wx = wrep + XOFF + (size_t)n0 * 32 + ln * 32 + q * 8;
#pragma unroll
        for (int s = 0; s < NSX; ++s) {
            int tap = 4 * s + q;                       // lane-quad = tap-slot
            if (tap > KK - 1) tap = KK - 1;            // pad slots: B = 0
            int ky = tap / K;
            int kx = tap - ky * K;
            int xoff = (ky * PW + kx) * 8;
            const bf16* ws = wx + (size_t)s * COUT * 32;
            bf16x8 bfr[WN];
#pragma unroll
            for (int u = 0; u < WN; ++u)
                bfr[u] = *(const bf16x8*)(ws + u * 512);
            bf16x8 afr[8];
#pragma unroll
            for (int t = 0; t < 8; ++t)
                afr[t] = *(const bf16x8*)(s_in + xabase[t] + xoff);
#pragma unroll
            for (int t = 0; t < 8; ++t)
#pragma unroll
                for (int u = 0; u < WN; ++u)
                    acc[t][u] = __builtin_amdgcn_mfma_f32_16x16x32_bf16(
                        afr[t], bfr[u], acc[t][u], 0, 0, 0);
        }
    }

    // ---- epilogue: bias + relu (+store) + gap/dct reduction ----
    float gsum[WN], dsum[WN], bv[WN];
#pragma unroll
    for (int u = 0; u < WN; ++u) {
        gsum[u] = 0.f; dsum[u] = 0.f;
        bv[u] = bias[n0 + u * 16 + ln];
    }

#pragma unroll
    for (int t = 0; t < 8; ++t) {
        const int lr = wavem * 2 + (t >> 2);
        const int gr = o0 + lr;
        const float wrow = dctw[gr];
        const int ct = (t & 3) * 16;
#pragma unroll
        for (int r = 0; r < 4; ++r) {
            const int gc = ct + q * 4 + r;         // C/D: m = (lane>>4)*4 + reg
            const float wcd = dctw[gc] * wrow;
#pragma unroll
            for (int u = 0; u < WN; ++u) {
                float v = fmaxf(acc[t][u][r] + bv[u], 0.f);
                if constexpr (STORE) {
                    int ch = n0 + u * 16 + ln;
                    act_out[(img * OPL + (ch >> 3)) * PLE +
                            ((size_t)(gr + 3) * PW + (gc + 3)) * 8 + (ch & 7)] = (bf16)v;
                }
                gsum[u] += v;
                dsum[u] = fmaf(v, wcd, dsum[u]);
            }
        }
    }

    const int cb = br * 448 + stage_coff;
#pragma unroll
    for (int u = 0; u < WN; ++u) {
        float gv = gsum[u], dv = dsum[u];
        gv += __shfl_xor(gv, 16, 64); gv += __shfl_xor(gv, 32, 64);
        dv += __shfl_xor(dv, 16, 64); dv += __shfl_xor(dv, 32, 64);
        if (q == 0) {
            int ch = cb + n0 + u * 16 + ln;
            atomicAdd(&gap_sum[b * NCH + ch], gv);
            atomicAdd(&dct_sum[b * NCH + ch], dv);
        }
    }
}

// ---------------------------------------------------------------------------
__global__ __launch_bounds__(256) void head_kernel(
    const float* __restrict__ gap_sum, const float* __restrict__ dct_sum,
    const float* __restrict__ gap_w, const float* __restrict__ gap_b,
    const float* __restrict__ dct_w, const float* __restrict__ dct_b,
    const float* __restrict__ gamma, const float* __restrict__ beta,
    const float* __restrict__ mean, const float* __restrict__ var,
    float* __restrict__ out)
{
    const int blk = blockIdx.x;
    const int b = blk / 24;
    const int rem = blk - b * 24;
    const int kind = rem / 12;
    const int i = rem - kind * 12;
    const int tid = threadIdx.x;

    float partial = 0.f;
    if (kind == 0) {
        for (int cc = tid; cc < NCH; cc += 256)
            partial += gap_sum[b * NCH + cc] * (1.f / 4096.f) * gap_w[i * NCH + cc];
    } else {
        for (int cc = tid; cc < NCH; cc += 256) {
            float f = dct_sum[b * NCH + cc];
            f = gamma[cc] * (f - mean[cc]) * rsqrtf(var[cc] + 1e-5f) + beta[cc];
            partial += f * dct_w[i * NCH + cc];
        }
    }
#pragma unroll
    for (int off = 32; off > 0; off >>= 1) partial += __shfl_down(partial, off, 64);
    __shared__ float red[4];
    if ((tid & 63) == 0) red[tid >> 6] = partial;
    __syncthreads();
    if (tid == 0) {
        float tot = red[0] + red[1] + red[2] + red[3];
        tot += (kind == 0 ? gap_b[i] : dct_b[i]);
        out[kind * (NB * 12) + b * 12 + i] = tot;
    }
}

// ---------------------------------------------------------------------------
extern "C" void kernel_launch(void* const* d_in, const int* in_sizes, int n_in,
                              void* d_out, int out_size, void* d_ws, size_t ws_size,
                              hipStream_t stream)
{
    const float* x = (const float*)d_in[0];

    float* fws = (float*)d_ws;
    float* dctw    = fws;                      // 64
    float* gap_sum = fws + 64;                 // 16*1792
    float* dct_sum = gap_sum + NB * NCH;       // 16*1792
    bf16* bws = (bf16*)(dct_sum + NB * NCH);   // 229,632 B offset (16B aligned)

    const size_t WALL_E = 4 * WBR;                 // 7,806,976
    const size_t XP_E   = (size_t)NB * 2 * PLE;    // 1,290,240 (single plane/g)
    const size_t A3_BR  = (size_t)NB * 8 * PLE;    // per branch
    const size_t A5_BR  = (size_t)NB * 16 * PLE;   // per branch

    const size_t fixed_b = 229632 + 2 * (WALL_E + XP_E);
    int nbr = 1, br_bits = 0;
    if (ws_size >= fixed_b + 2 * 4 * (A3_BR + A5_BR)) { nbr = 4; br_bits = 2; }
    else if (ws_size >= fixed_b + 2 * 2 * (A3_BR + A5_BR)) { nbr = 2; br_bits = 1; }
    const int br_mask = nbr - 1;

    bf16* wall = bws;
    bf16* xp   = wall + WALL_E;
    bf16* a3p  = xp + XP_E;
    bf16* a5p  = a3p + (size_t)nbr * A3_BR;

    hipLaunchKernelGGL(init_kernel, dim3((NB * NCH + 255) / 256), dim3(256), 0, stream,
                       gap_sum, dct_sum, dctw);

    // halo-only zeroing of xp + a3 + a5 (contiguous planar-8 planes)
    const int nplanes = NB * 2 + nbr * NB * (8 + 16);
    hipLaunchKernelGGL(halo_zero, dim3((nplanes * 944 + 255) / 256), dim3(256), 0, stream,
                       xp, nplanes);

    hipLaunchKernelGGL(prep_x_kernel, dim3((NB * 2 * NPIX) / 256), dim3(256), 0, stream, x, xp);

    PtrQuad w3q = {{(const float*)d_in[1], (const float*)d_in[7], (const float*)d_in[13], (const float*)d_in[19]}};
    PtrQuad b3q = {{(const float*)d_in[2], (const float*)d_in[8], (const float*)d_in[14], (const float*)d_in[20]}};
    PtrQuad w5q = {{(const float*)d_in[3], (const float*)d_in[9], (const float*)d_in[15], (const float*)d_in[21]}};
    PtrQuad b5q = {{(const float*)d_in[4], (const float*)d_in[10], (const float*)d_in[16], (const float*)d_in[22]}};
    PtrQuad w7q = {{(const float*)d_in[5], (const float*)d_in[11], (const float*)d_in[17], (const float*)d_in[23]}};
    PtrQuad b7q = {{(const float*)d_in[6], (const float*)d_in[12], (const float*)d_in[18], (const float*)d_in[24]}};

    hipLaunchKernelGGL((prep_w_all<3, 0, 0, 64>), dim3((4 * W3SZ + 255) / 256), dim3(256), 0, stream,
                       w3q, wall);
    hipLaunchKernelGGL((prep_w_all<5, 2, 64, 128>), dim3((4 * W5SZ + 255) / 256), dim3(256), 0, stream,
                       w5q, wall + W3SZ);
    hipLaunchKernelGGL((prep_w_all<7, 4, 128, 256>), dim3((4 * W7SZ + 255) / 256), dim3(256), 0, stream,
                       w7q, wall + W3SZ + W5SZ);

    for (int br0 = 0; br0 < 4; br0 += nbr) {
        hipLaunchKernelGGL((conv_mfma<3, 0, 64, 64, true>), dim3(16 * nbr, 1, NB), dim3(256), 0, stream,
                           (const bf16*)nullptr, xp, wall, 0, b3q,
                           a3p, gap_sum, dct_sum, 0, dctw, br0, br_mask, br_bits);
        hipLaunchKernelGGL((conv_mfma<5, 2, 128, 128, true>), dim3(16 * nbr, 1, NB), dim3(256), 0, stream,
                           a3p, xp, wall, W3SZ, b5q,
                           a5p, gap_sum, dct_sum, 64, dctw, br0, br_mask, br_bits);
        hipLaunchKernelGGL((conv_mfma<7, 4, 256, 128, false>), dim3(16 * nbr, 2, NB), dim3(256), 0, stream,
                           a5p, xp, wall, W3SZ + W5SZ, b7q,
                           (bf16*)nullptr, gap_sum, dct_sum, 192, dctw, br0, br_mask, br_bits);
    }

    hipLaunchKernelGGL(head_kernel, dim3(NB * 24), dim3(256), 0, stream,
                       gap_sum, dct_sum,
                       (const float*)d_in[25], (const float*)d_in[26],
                       (const float*)d_in[27], (const float*)d_in[28],
                       (const float*)d_in[29], (const float*)d_in[30],
                       (const float*)d_in[31], (const float*)d_in[32],
                       (float*)d_out);
}

// Round 13
// 868.373 us; speedup vs baseline: 1.0601x; 1.0124x over previous
//
#include <hip/hip_runtime.h>
#include <hip/hip_bf16.h>
#include <math.h>

#define HW 64
#define NPIX 4096
#define NB 16
#define NCH 1792
#define PW 72                 // padded width (units of 8ch)
#define PROWS 70              // padded rows (64 + 2*3 halo)
#define PLANE (PROWS * PW)    // 5040 units per 8-ch plane

typedef __bf16 bf16;
typedef __bf16 bf16x8 __attribute__((ext_vector_type(8)));
typedef float f32x4 __attribute__((ext_vector_type(4)));

struct PtrQuad { const float* p[4]; };

constexpr size_t PLE = (size_t)PLANE * 8;      // bf16 elements per plane

// x-part MFMA steps: 4 taps x 8ch per K=32 step
constexpr int nstepx(int K) { return (K * K + 3) / 4; }

// repacked-weight sizes (bf16 elements) per branch:
//   act part [K*K][ACT_CHUNKS][COUT][32] + x part [NSX][COUT][32]
constexpr size_t W3SZ = (size_t)nstepx(3) * 64 * 32;                        // 6144
constexpr size_t W5SZ = (size_t)25 * 2 * 128 * 32 + nstepx(5) * 128 * 32;   // 233472
constexpr size_t W7SZ = (size_t)49 * 4 * 256 * 32 + nstepx(7) * 256 * 32;   // 1712128
constexpr size_t WBR  = W3SZ + W5SZ + W7SZ;                                 // 1951744

// ---------------------------------------------------------------------------
// weight repack element: act part [K*K][ACT_CHUNKS][COUT][32] (ci=chunk*32+cc)
// + x part [NSX][COUT][32] where 32 = slot(4 taps)*8 + ch (ch<3 real, else 0)
template <int K, int ACT_CHUNKS, int CIN_ACT, int COUT>
__device__ __forceinline__ void repack_one(int gidx, const PtrQuad& src,
                                           bf16* __restrict__ dst) {
    constexpr int CIN = CIN_ACT + 3;
    constexpr int KK = K * K;
    constexpr int NSX = (KK + 3) / 4;
    constexpr int ACT_TOT = KK * ACT_CHUNKS * COUT * 32;
    constexpr int X_TOT = NSX * COUT * 32;
    constexpr int TOT = ACT_TOT + X_TOT;
    constexpr int ACD = ACT_CHUNKS ? ACT_CHUNKS : 1;
    int br = gidx / TOT;
    int idx = gidx - br * TOT;
    const float* w = src.p[br];
    float v;
    if (idx < ACT_TOT) {
        int cc = idx & 31;
        int co = (idx >> 5) % COUT;
        int rest = idx / (32 * COUT);
        int chunk = rest % ACD;
        int ks = rest / ACD;
        int ky = ks / K, kx = ks % K;
        v = w[(((size_t)co * CIN + chunk * 32 + cc) * K + ky) * K + kx];
    } else {
        int xi = idx - ACT_TOT;
        int j = xi & 7;
        int slot = (xi >> 3) & 3;
        int co = (xi >> 5) % COUT;
        int s = xi / (32 * COUT);
        int tap = 4 * s + slot;
        if (tap < KK && j < 3) {
            int ky = tap / K, kx = tap % K;
            v = w[(((size_t)co * CIN + CIN_ACT + j) * K + ky) * K + kx];
        } else v = 0.f;
    }
    dst[(size_t)br * WBR + idx] = (bf16)v;
}

// ---------------------------------------------------------------------------
// mega-prep: ALL independent pre-conv work in one grid-stride launch.
//   s0: zero gap/dct sums (+ dctw[0..63])
//   s1: halo-only zero of planar-8 scratch (944 units/plane)
//   s2: x fp32 NCHW -> padded planar-8 bf16 (full 16B units, interiors)
//   s3/s4/s5: weight repack for conv3/conv5/conv7 (4 branches each)
// ---------------------------------------------------------------------------
__global__ __launch_bounds__(256) void mega_prep(
    const float* __restrict__ x,
    PtrQuad w3q, PtrQuad w5q, PtrQuad w7q,
    float* __restrict__ gap_sum, float* __restrict__ dct_sum,
    float* __restrict__ dctw,
    bf16* __restrict__ wall, bf16* __restrict__ xp, int nplanes)
{
    const long S0 = NB * NCH;
    const long S1 = (long)nplanes * 944;
    const long S2 = NB * 2 * NPIX;
    const long S3 = 4 * (long)W3SZ;
    const long S4 = 4 * (long)W5SZ;
    const long S5 = 4 * (long)W7SZ;
    const long TOTAL = S0 + S1 + S2 + S3 + S4 + S5;
    const long stride = (long)gridDim.x * 256;

    for (long t = (long)blockIdx.x * 256 + threadIdx.x; t < TOTAL; t += stride) {
        long r = t;
        if (r < S0) {
            gap_sum[r] = 0.f; dct_sum[r] = 0.f;
            if (r < HW) {
                int i = (int)r;
                float s = 0.f;
                for (int u = 0; u < 5; ++u) {
                    float scale = (u == 0) ? 0.125f : 0.17677669529663687f;
                    s += cosf(3.14159265358979323846f * (2.f * i + 1.f) * u / 128.f) * scale;
                }
                dctw[i] = s * 0.2f;
            }
            continue;
        }
        r -= S0;
        if (r < S1) {
            int p = (int)(r / 944), u = (int)(r - (long)p * 944);
            int row, col;
            if (u < 432) { row = u / PW; col = u - row * PW; if (row >= 3) row += 64; }
            else { int v = u - 432; row = 3 + (v >> 3); int c = v & 7; col = (c < 3) ? c : 64 + c; }
            bf16x8 z;
#pragma unroll
            for (int j = 0; j < 8; ++j) z[j] = (bf16)0.f;
            *(bf16x8*)(xp + ((size_t)p * PLANE + row * PW + col) * 8) = z;
            continue;
        }
        r -= S1;
        if (r < S2) {
            int tid = (int)r;
            int pix = tid & (NPIX - 1);
            int g = (tid >> 12) & 1;
            int b = tid >> 13;
            int h = pix >> 6, w = pix & 63;
            bf16x8 v;
#pragma unroll
            for (int j = 0; j < 8; ++j) v[j] = (bf16)0.f;
            for (int c = 0; c < 3; ++c)
                v[c] = (bf16)x[((size_t)(b * 6 + g * 3 + c)) * NPIX + pix];
            *(bf16x8*)(xp + ((size_t)(b * 2 + g) * PLANE + (size_t)(h + 3) * PW + (w + 3)) * 8) = v;
            continue;
        }
        r -= S2;
        if (r < S3) { repack_one<3, 0, 0, 64>((int)r, w3q, wall); continue; }
        r -= S3;
        if (r < S4) { repack_one<5, 2, 64, 128>((int)r, w5q, wall + W3SZ); continue; }
        r -= S4;
        repack_one<7, 4, 128, 256>((int)r, w7q, wall + W3SZ + W5SZ);
    }
}

// ---------------------------------------------------------------------------
// Implicit-GEMM conv, MFMA 16x16x32 bf16 — UNCHANGED from R12 (879us best):
// NBLK=128 / 2 blocks/CU, planar global_load_lds staging, tap-packed x-chunk
// riding the last act chunk's barrier pair, XCD branch pinning, JIT A/B
// loads (B-prefetch failed 3x: R4/R6/R9; TLP bump neutral: R11).
// ---------------------------------------------------------------------------
template <int K, int ACT_CHUNKS, int COUT, int NBLK, bool STORE>
__global__ __launch_bounds__(256, 2) void conv_mfma(
    const bf16* __restrict__ act_in,   // [lbr*NB+b][ACT_CHUNKS*4 planes][PLANE][8]
    const bf16* __restrict__ xpad,     // [b][g][PLANE][8]
    const bf16* __restrict__ wall, size_t stage_woff,
    PtrQuad biasq,
    bf16* __restrict__ act_out,        // [lbr*NB+b][COUT/8 planes][PLANE][8]
    float* __restrict__ gap_sum, float* __restrict__ dct_sum,
    int stage_coff, const float* __restrict__ dctw, int br0,
    int br_mask, int br_bits)
{
    constexpr int PAD = K / 2;
    constexpr int COFF = 3 - PAD;          // layout pad (3) minus conv pad
    constexpr int HR = 4 + K - 1;          // staged rows (4 out rows + halo)
    constexpr int UN = HR * PW;            // 16B units in one staged plane-tile
    constexpr int NI = (UN + 63) / 64;     // DMA insts per wave (act: 1 seg/wave)
    constexpr int WN = NBLK / 32;          // n-frags per wave
    constexpr int KK = K * K;
    constexpr int NSX = (KK + 3) / 4;      // x-part MFMA steps
    constexpr int CW = ACT_CHUNKS * COUT * 32;   // act tap stride in wrep
    constexpr int XOFF = KK * ACT_CHUNKS * COUT * 32;
    constexpr int OPL = COUT / 8;          // output planes
    constexpr int XSEG = ACT_CHUNKS ? 4 : 0;     // x plane's LDS segment
    constexpr int NSEG = ACT_CHUNKS ? 5 : 1;

    __shared__ __align__(16) bf16 s_in[NSEG * HR * PW * 8];

    const int tid = threadIdx.x;
    const int lane = tid & 63;
    const int wv = tid >> 6;
    const int wavem = wv >> 1;             // 0..1 -> rows [wavem*2, wavem*2+2)
    const int wn = wv & 1;
    const int q = lane >> 4;
    const int ln = lane & 15;

    const int bx = blockIdx.x;
    const int lbr = bx & br_mask;          // branch in LOW bits -> XCD pinning
    const int row = bx >> br_bits;
    const int b = blockIdx.z;
    const int br = br0 + lbr;
    const int g = br >> 1;

    const int o0 = row * 4;
    const int prow0 = o0 + COFF;           // first staged padded row
    const int n0 = blockIdx.y * NBLK + wn * (NBLK / 2);

    const bf16* wrep = wall + (size_t)br * WBR + stage_woff;
    const float* bias = biasq.p[br];
    const size_t img = (size_t)(lbr * NB + b);

    // A-frag base offsets for act chunks (q = k-segment plane)
    int abase[8];
#pragma unroll
    for (int t = 0; t < 8; ++t) {
        int lr = wavem * 2 + (t >> 2);
        int ct = (t & 3) * 16;
        abase[t] = ((q * HR + lr) * PW + ct + ln + COFF) * 8;
    }

    f32x4 acc[8][WN];
#pragma unroll
    for (int t = 0; t < 8; ++t)
#pragma unroll
        for (int u = 0; u < WN; ++u) acc[t][u] = f32x4{0.f, 0.f, 0.f, 0.f};

    const bf16* xgb = xpad + (size_t)(b * 2 + g) * PLE + (size_t)prow0 * PW * 8;
    constexpr int PERW = (UN + 3) / 4;     // x units per wave
    constexpr int NIX = (PERW + 63) / 64;

    // ---- act 32-ch chunks (x plane rides the last chunk's barrier) ----
#pragma unroll 1
    for (int chunk = 0; chunk < ACT_CHUNKS; ++chunk) {
        __syncthreads();                   // buffer free (prev reads done)
        {
            const bf16* pl = act_in + (img * (ACT_CHUNKS * 4) + chunk * 4 + wv) * PLE;
            const bf16* gb = pl + (size_t)prow0 * PW * 8;
            bf16* lb = s_in + (size_t)wv * HR * PW * 8;
#pragma unroll
            for (int i = 0; i < NI; ++i) {
                int u = i * 64 + lane;
                if (UN % 64 == 0 || u < UN)
                    __builtin_amdgcn_global_load_lds(
                        (const __attribute__((address_space(1))) void*)(gb + (size_t)u * 8),
                        (__attribute__((address_space(3))) void*)(lb + i * 512),
                        16, 0, 0);
            }
        }
        if (chunk == ACT_CHUNKS - 1) {     // stage x plane into segment 4
            const int u0 = wv * PERW;
            bf16* lb = s_in + (size_t)(XSEG * HR * PW + u0) * 8;
#pragma unroll
            for (int i = 0; i < NIX; ++i) {
                int u = i * 64 + lane;
                if (u < PERW && u0 + u < UN)
                    __builtin_amdgcn_global_load_lds(
                        (const __attribute__((address_space(1))) void*)(xgb + (size_t)(u0 + u) * 8),
                        (__attribute__((address_space(3))) void*)(lb + i * 512),
                        16, 0, 0);
            }
        }
        __syncthreads();                   // DMA landed

        const bf16* wchunk = wrep + ((size_t)chunk * COUT + n0) * 32 + ln * 32 + q * 8;

#pragma unroll 1
        for (int ky = 0; ky < K; ++ky) {
            const int kyoff = ky * PW * 8;
#pragma unroll
            for (int kx = 0; kx < K; ++kx) {
                const bf16* wstep = wchunk + (size_t)(ky * K + kx) * CW;
                bf16x8 bfr[WN];
#pragma unroll
                for (int u = 0; u < WN; ++u)
                    bfr[u] = *(const bf16x8*)(wstep + u * 512);
                const int koff = kyoff + kx * 8;
                bf16x8 afr[8];
#pragma unroll
                for (int t = 0; t < 8; ++t)
                    afr[t] = *(const bf16x8*)(s_in + abase[t] + koff);
#pragma unroll
                for (int t = 0; t < 8; ++t)
#pragma unroll
                    for (int u = 0; u < WN; ++u)
                        acc[t][u] = __builtin_amdgcn_mfma_f32_16x16x32_bf16(
                            afr[t], bfr[u], acc[t][u], 0, 0, 0);
            }
        }
    }

    // ---- x tap-packed part: NSX steps of (4 taps x 8 ch) ----
    if constexpr (ACT_CHUNKS == 0) {       // conv3: stage x alone
        __syncthreads();
        {
            const int u0 = wv * PERW;
            bf16* lb = s_in + (size_t)u0 * 8;
#pragma unroll
            for (int i = 0; i < NIX; ++i) {
                int u = i * 64 + lane;
                if (u < PERW && u0 + u < UN)
                    __builtin_amdgcn_global_load_lds(
                        (const __attribute__((address_space(1))) void*)(xgb + (size_t)(u0 + u) * 8),
                        (__attribute__((address_space(3))) void*)(lb + i * 512),
                        16, 0, 0);
            }
        }
        __syncthreads();
    }
    // (ACT_CHUNKS>0: x already landed before the last chunk's barrier)

    {
        int xabase[8];
#pragma unroll
        for (int t = 0; t < 8; ++t) {
            int lr = wavem * 2 + (t >> 2);
            int ct = (t & 3) * 16;
            xabase[t] = ((XSEG * HR + lr) * PW + ct + ln + COFF) * 8;
        }
        const bf16* wx = wrep + XOFF + (size_t)n0 * 32 + ln * 32 + q * 8;
#pragma unroll
        for (int s = 0; s < NSX; ++s) {
            int tap = 4 * s + q;                       // lane-quad = tap-slot
            if (tap > KK - 1) tap = KK - 1;            // pad slots: B = 0
            int ky = tap / K;
            int kx = tap - ky * K;
            int xoff = (ky * PW + kx) * 8;
            const bf16* ws = wx + (size_t)s * COUT * 32;
            bf16x8 bfr[WN];
#pragma unroll
            for (int u = 0; u < WN; ++u)
                bfr[u] = *(const bf16x8*)(ws + u * 512);
            bf16x8 afr[8];
#pragma unroll
            for (int t = 0; t < 8; ++t)
                afr[t] = *(const bf16x8*)(s_in + xabase[t] + xoff);
#pragma unroll
            for (int t = 0; t < 8; ++t)
#pragma unroll
                for (int u = 0; u < WN; ++u)
                    acc[t][u] = __builtin_amdgcn_mfma_f32_16x16x32_bf16(
                        afr[t], bfr[u], acc[t][u], 0, 0, 0);
        }
    }

    // ---- epilogue: bias + relu (+store) + gap/dct reduction ----
    float gsum[WN], dsum[WN], bv[WN];
#pragma unroll
    for (int u = 0; u < WN; ++u) {
        gsum[u] = 0.f; dsum[u] = 0.f;
        bv[u] = bias[n0 + u * 16 + ln];
    }

#pragma unroll
    for (int t = 0; t < 8; ++t) {
        const int lr = wavem * 2 + (t >> 2);
        const int gr = o0 + lr;
        const float wrow = dctw[gr];
        const int ct = (t & 3) * 16;
#pragma unroll
        for (int r = 0; r < 4; ++r) {
            const int gc = ct + q * 4 + r;         // C/D: m = (lane>>4)*4 + reg
            const float wcd = dctw[gc] * wrow;
#pragma unroll
            for (int u = 0; u < WN; ++u) {
                float v = fmaxf(acc[t][u][r] + bv[u], 0.f);
                if constexpr (STORE) {
                    int ch = n0 + u * 16 + ln;
                    act_out[(img * OPL + (ch >> 3)) * PLE +
                            ((size_t)(gr + 3) * PW + (gc + 3)) * 8 + (ch & 7)] = (bf16)v;
                }
                gsum[u] += v;
                dsum[u] = fmaf(v, wcd, dsum[u]);
            }
        }
    }

    const int cb = br * 448 + stage_coff;
#pragma unroll
    for (int u = 0; u < WN; ++u) {
        float gv = gsum[u], dv = dsum[u];
        gv += __shfl_xor(gv, 16, 64); gv += __shfl_xor(gv, 32, 64);
        dv += __shfl_xor(dv, 16, 64); dv += __shfl_xor(dv, 32, 64);
        if (q == 0) {
            int ch = cb + n0 + u * 16 + ln;
            atomicAdd(&gap_sum[b * NCH + ch], gv);
            atomicAdd(&dct_sum[b * NCH + ch], dv);
        }
    }
}

// ---------------------------------------------------------------------------
__global__ __launch_bounds__(256) void head_kernel(
    const float* __restrict__ gap_sum, const float* __restrict__ dct_sum,
    const float* __restrict__ gap_w, const float* __restrict__ gap_b,
    const float* __restrict__ dct_w, const float* __restrict__ dct_b,
    const float* __restrict__ gamma, const float* __restrict__ beta,
    const float* __restrict__ mean, const float* __restrict__ var,
    float* __restrict__ out)
{
    const int blk = blockIdx.x;
    const int b = blk / 24;
    const int rem = blk - b * 24;
    const int kind = rem / 12;
    const int i = rem - kind * 12;
    const int tid = threadIdx.x;

    float partial = 0.f;
    if (kind == 0) {
        for (int cc = tid; cc < NCH; cc += 256)
            partial += gap_sum[b * NCH + cc] * (1.f / 4096.f) * gap_w[i * NCH + cc];
    } else {
        for (int cc = tid; cc < NCH; cc += 256) {
            float f = dct_sum[b * NCH + cc];
            f = gamma[cc] * (f - mean[cc]) * rsqrtf(var[cc] + 1e-5f) + beta[cc];
            partial += f * dct_w[i * NCH + cc];
        }
    }
#pragma unroll
    for (int off = 32; off > 0; off >>= 1) partial += __shfl_down(partial, off, 64);
    __shared__ float red[4];
    if ((tid & 63) == 0) red[tid >> 6] = partial;
    __syncthreads();
    if (tid == 0) {
        float tot = red[0] + red[1] + red[2] + red[3];
        tot += (kind == 0 ? gap_b[i] : dct_b[i]);
        out[kind * (NB * 12) + b * 12 + i] = tot;
    }
}

// ---------------------------------------------------------------------------
extern "C" void kernel_launch(void* const* d_in, const int* in_sizes, int n_in,
                              void* d_out, int out_size, void* d_ws, size_t ws_size,
                              hipStream_t stream)
{
    const float* x = (const float*)d_in[0];

    float* fws = (float*)d_ws;
    float* dctw    = fws;                      // 64
    float* gap_sum = fws + 64;                 // 16*1792
    float* dct_sum = gap_sum + NB * NCH;       // 16*1792
    bf16* bws = (bf16*)(dct_sum + NB * NCH);   // 229,632 B offset (16B aligned)

    const size_t WALL_E = 4 * WBR;                 // 7,806,976
    const size_t XP_E   = (size_t)NB * 2 * PLE;    // 1,290,240 (single plane/g)
    const size_t A3_BR  = (size_t)NB * 8 * PLE;    // per branch
    const size_t A5_BR  = (size_t)NB * 16 * PLE;   // per branch

    const size_t fixed_b = 229632 + 2 * (WALL_E + XP_E);
    int nbr = 1, br_bits = 0;
    if (ws_size >= fixed_b + 2 * 4 * (A3_BR + A5_BR)) { nbr = 4; br_bits = 2; }
    else if (ws_size >= fixed_b + 2 * 2 * (A3_BR + A5_BR)) { nbr = 2; br_bits = 1; }
    const int br_mask = nbr - 1;

    bf16* wall = bws;
    bf16* xp   = wall + WALL_E;
    bf16* a3p  = xp + XP_E;
    bf16* a5p  = a3p + (size_t)nbr * A3_BR;

    PtrQuad w3q = {{(const float*)d_in[1], (const float*)d_in[7], (const float*)d_in[13], (const float*)d_in[19]}};
    PtrQuad b3q = {{(const float*)d_in[2], (const float*)d_in[8], (const float*)d_in[14], (const float*)d_in[20]}};
    PtrQuad w5q = {{(const float*)d_in[3], (const float*)d_in[9], (const float*)d_in[15], (const float*)d_in[21]}};
    PtrQuad b5q = {{(const float*)d_in[4], (const float*)d_in[10], (const float*)d_in[16], (const float*)d_in[22]}};
    PtrQuad w7q = {{(const float*)d_in[5], (const float*)d_in[11], (const float*)d_in[17], (const float*)d_in[23]}};
    PtrQuad b7q = {{(const float*)d_in[6], (const float*)d_in[12], (const float*)d_in[18], (const float*)d_in[24]}};

    // one grid-stride launch for ALL independent prep work
    const int nplanes = NB * 2 + nbr * NB * (8 + 16);
    hipLaunchKernelGGL(mega_prep, dim3(2048), dim3(256), 0, stream,
                       x, w3q, w5q, w7q, gap_sum, dct_sum, dctw, wall, xp, nplanes);

    for (int br0 = 0; br0 < 4; br0 += nbr) {
        hipLaunchKernelGGL((conv_mfma<3, 0, 64, 64, true>), dim3(16 * nbr, 1, NB), dim3(256), 0, stream,
                           (const bf16*)nullptr, xp, wall, 0, b3q,
                           a3p, gap_sum, dct_sum, 0, dctw, br0, br_mask, br_bits);
        hipLaunchKernelGGL((conv_mfma<5, 2, 128, 128, true>), dim3(16 * nbr, 1, NB), dim3(256), 0, stream,
                           a3p, xp, wall, W3SZ, b5q,
                           a5p, gap_sum, dct_sum, 64, dctw, br0, br_mask, br_bits);
        hipLaunchKernelGGL((conv_mfma<7, 4, 256, 128, false>), dim3(16 * nbr, 2, NB), dim3(256), 0, stream,
                           a5p, xp, wall, W3SZ + W5SZ, b7q,
                           (bf16*)nullptr, gap_sum, dct_sum, 192, dctw, br0, br_mask, br_bits);
    }

    hipLaunchKernelGGL(head_kernel, dim3(NB * 24), dim3(256), 0, stream,
                       gap_sum, dct_sum,
                       (const float*)d_in[25], (const float*)d_in[26],
                       (const float*)d_in[27], (const float*)d_in[28],
                       (const float*)d_in[29], (const float*)d_in[30],
                       (const float*)d_in[31], (const float*)d_in[32],
                       (float*)d_out);
}